// Round 16
// baseline (643.860 us; speedup 1.0000x reference)
//
#include <hip/hip_runtime.h>
#include <hip/hip_bf16.h>

#define NN 50000
#define NE 600000
#define HD 128
#define DET_SAMPLES 65536
#define NBLK 196                     // ceil((NN+1)/256)
#define GROWS 64                     // rows per GEMM block
#define GGRID ((NN + GROWS - 1)/GROWS)

typedef unsigned short ushort_t;

__device__ __forceinline__ float sigmoidf_(float x){ return 1.f/(1.f+__expf(-x)); }

__device__ __forceinline__ ushort_t f2bf(float f){
  unsigned int u = __float_as_uint(f);
  unsigned int r = (u + 0x7FFFu + ((u >> 16) & 1u)) >> 16;   // RNE
  return (ushort_t)r;
}

__device__ __forceinline__ float bflo(unsigned u){ return __uint_as_float(u << 16); }
__device__ __forceinline__ float bfhi(unsigned u){ return __uint_as_float(u & 0xFFFF0000u); }

// ---------------- diagnostic scalar write (env tripwire) ----------------
__global__ void write_scalar_kernel(float* __restrict__ p, float v){ p[0] = v; }

// ---------------- edge_index dtype detect + decode (+ dst histogram) ----------------
__global__ void detect_kernel(const unsigned int* __restrict__ w, int* __restrict__ flag){
  int i = blockIdx.x*256 + threadIdx.x;           // [0, DET_SAMPLES)
  int z = (w[2*i + 1] == 0u) ? 1 : 0;
  atomicAdd(flag, z);
}

__global__ void extract_kernel(const void* __restrict__ ei, const int* __restrict__ flag,
                               int* __restrict__ srcW, int* __restrict__ dstW,
                               int* __restrict__ counts){
  const int e = blockIdx.x*256 + threadIdx.x;
  if (e >= NE) return;
  int s, d;
  if (*flag > (DET_SAMPLES/2)){
    const long long* p = (const long long*)ei;
    s = (int)p[e]; d = (int)p[NE + e];
  } else {
    const int* p = (const int*)ei;
    s = p[e]; d = p[NE + e];
  }
  srcW[e] = s; dstW[e] = d;
  atomicAdd(&counts[d], 1);
}

// ---------------- hierarchical exclusive scan of counts[NN] ----------------
__global__ __launch_bounds__(256) void scanA_kernel(const int* __restrict__ counts,
                                                    int* __restrict__ partial){
  __shared__ int s[256];
  const int t = threadIdx.x;
  const int idx = blockIdx.x*256 + t;
  s[t] = (idx < NN) ? counts[idx] : 0;
  __syncthreads();
  for (int off = 128; off > 0; off >>= 1){
    if (t < off) s[t] += s[t + off];
    __syncthreads();
  }
  if (t == 0) partial[blockIdx.x] = s[0];
}

__global__ __launch_bounds__(256) void scanB_kernel(const int* __restrict__ partial,
                                                    int* __restrict__ bOff){
  __shared__ int s[256];
  const int t = threadIdx.x;
  const int v = (t < NBLK) ? partial[t] : 0;
  s[t] = v;
  __syncthreads();
  for (int off = 1; off < 256; off <<= 1){
    int add = (t >= off) ? s[t - off] : 0;
    __syncthreads();
    s[t] += add;
    __syncthreads();
  }
  if (t < NBLK) bOff[t] = s[t] - v;        // exclusive
}

__global__ __launch_bounds__(256) void scanC_kernel(const int* __restrict__ counts,
    const int* __restrict__ bOff, int* __restrict__ row_start, int* __restrict__ cursor){
  __shared__ int s[256];
  const int t = threadIdx.x;
  const int idx = blockIdx.x*256 + t;
  const int c = (idx < NN) ? counts[idx] : 0;
  s[t] = c;
  __syncthreads();
  for (int off = 1; off < 256; off <<= 1){
    int add = (t >= off) ? s[t - off] : 0;
    __syncthreads();
    s[t] += add;
    __syncthreads();
  }
  const int excl = bOff[blockIdx.x] + s[t] - c;
  if (idx < NN){ row_start[idx] = excl; cursor[idx] = excl; }
  else if (idx == NN){ row_start[NN] = excl; }
}

// fill: also writes CSR-ordered src (srcS) so msg needs no eids->srcI indirection
__global__ void fill_kernel(const int* __restrict__ dstI, const int* __restrict__ srcI,
                            int* __restrict__ cursor, int* __restrict__ eids,
                            int* __restrict__ srcS){
  int e = blockIdx.x*256 + threadIdx.x;
  if (e < NE){
    int p = atomicAdd(&cursor[dstI[e]], 1);
    eids[p] = e;
    srcS[p] = srcI[e];
  }
}

// ---------------- GEMM (single W): out = act(in @ W + bias) ----------------
// W from L2 (coalesced float4/k); LDS holds the 64-row input tile, read as float4.
// FMA order: k ascending per output -> bitwise-identical to previous rounds.
__global__ __launch_bounds__(256) void gemm_h(const float* __restrict__ in,
    const float* __restrict__ W, const float* __restrict__ bias,
    float* __restrict__ outF, ushort_t* __restrict__ outB, int n, int doRelu)
{
  __shared__ float Is[GROWS*HD];                 // 32 KB
  const int t = threadIdx.x;
  const int row0 = blockIdx.x * GROWS;
  const float4* src = (const float4*)(in + (size_t)row0*HD);
  float4* dst4 = (float4*)Is;
  #pragma unroll
  for (int i = 0; i < 8; ++i){
    int idx = t + i*256;                         // 2048 float4
    float4 v = make_float4(0.f,0.f,0.f,0.f);
    if (row0 + (idx >> 5) < n) v = src[idx];
    dst4[idx] = v;
  }
  __syncthreads();
  const int c4 = t & 31;                         // float4 column
  const int rg = t >> 5;                         // 0..7; rows m*8+rg
  float4 acc[8];
  #pragma unroll
  for (int m = 0; m < 8; ++m) acc[m] = make_float4(0.f,0.f,0.f,0.f);
  #pragma unroll 4
  for (int kq = 0; kq < HD/4; ++kq){
    const float4 w0 = ((const float4*)(W + (size_t)(4*kq+0)*HD))[c4];
    const float4 w1 = ((const float4*)(W + (size_t)(4*kq+1)*HD))[c4];
    const float4 w2 = ((const float4*)(W + (size_t)(4*kq+2)*HD))[c4];
    const float4 w3 = ((const float4*)(W + (size_t)(4*kq+3)*HD))[c4];
    #pragma unroll
    for (int m = 0; m < 8; ++m){
      const float4 a = *(const float4*)(Is + (m*8+rg)*HD + 4*kq);  // broadcast b128
      acc[m].x = fmaf(a.x, w0.x, acc[m].x);
      acc[m].y = fmaf(a.x, w0.y, acc[m].y);
      acc[m].z = fmaf(a.x, w0.z, acc[m].z);
      acc[m].w = fmaf(a.x, w0.w, acc[m].w);
      acc[m].x = fmaf(a.y, w1.x, acc[m].x);
      acc[m].y = fmaf(a.y, w1.y, acc[m].y);
      acc[m].z = fmaf(a.y, w1.z, acc[m].z);
      acc[m].w = fmaf(a.y, w1.w, acc[m].w);
      acc[m].x = fmaf(a.z, w2.x, acc[m].x);
      acc[m].y = fmaf(a.z, w2.y, acc[m].y);
      acc[m].z = fmaf(a.z, w2.z, acc[m].z);
      acc[m].w = fmaf(a.z, w2.w, acc[m].w);
      acc[m].x = fmaf(a.w, w3.x, acc[m].x);
      acc[m].y = fmaf(a.w, w3.y, acc[m].y);
      acc[m].z = fmaf(a.w, w3.z, acc[m].z);
      acc[m].w = fmaf(a.w, w3.w, acc[m].w);
    }
  }
  float4 b = make_float4(0.f,0.f,0.f,0.f);
  if (bias) b = ((const float4*)bias)[c4];
  #pragma unroll
  for (int m = 0; m < 8; ++m){
    const int r = row0 + m*8 + rg;
    if (r >= n) continue;
    float4 x = acc[m];
    x.x += b.x; x.y += b.y; x.z += b.z; x.w += b.w;
    if (doRelu){
      x.x = fmaxf(x.x, 0.f); x.y = fmaxf(x.y, 0.f);
      x.z = fmaxf(x.z, 0.f); x.w = fmaxf(x.w, 0.f);
    }
    if (outF) ((float4*)(outF + (size_t)r*HD))[c4] = x;
    if (outB){
      ushort4 p;
      p.x = f2bf(x.x); p.y = f2bf(x.y); p.z = f2bf(x.z); p.w = f2bf(x.w);
      ((ushort4*)(outB + (size_t)r*HD))[c4] = p;
    }
  }
}

// ---------------- fused U/V GEMM: U = in@Wu + bu, V = in@Wv (both bf16 out) ----------
__global__ __launch_bounds__(256) void gemm_uv(const float* __restrict__ in,
    const float* __restrict__ Wu, const float* __restrict__ Wv,
    const float* __restrict__ biasU,
    ushort_t* __restrict__ outU, ushort_t* __restrict__ outV, int n)
{
  __shared__ float Is[GROWS*HD];                 // 32 KB
  const int t = threadIdx.x;
  const int row0 = blockIdx.x * GROWS;
  const float4* src = (const float4*)(in + (size_t)row0*HD);
  float4* dst4 = (float4*)Is;
  #pragma unroll
  for (int i = 0; i < 8; ++i){
    int idx = t + i*256;
    float4 v = make_float4(0.f,0.f,0.f,0.f);
    if (row0 + (idx >> 5) < n) v = src[idx];
    dst4[idx] = v;
  }
  __syncthreads();
  const int c4 = t & 31;
  const int rg = t >> 5;
  float4 aU[8], aV[8];
  #pragma unroll
  for (int m = 0; m < 8; ++m){
    aU[m] = make_float4(0.f,0.f,0.f,0.f);
    aV[m] = make_float4(0.f,0.f,0.f,0.f);
  }
  #pragma unroll 2
  for (int kq = 0; kq < HD/4; ++kq){
    float4 wu[4], wv[4];
    #pragma unroll
    for (int j = 0; j < 4; ++j){
      wu[j] = ((const float4*)(Wu + (size_t)(4*kq+j)*HD))[c4];
      wv[j] = ((const float4*)(Wv + (size_t)(4*kq+j)*HD))[c4];
    }
    #pragma unroll
    for (int m = 0; m < 8; ++m){
      const float4 a = *(const float4*)(Is + (m*8+rg)*HD + 4*kq);
      const float av[4] = {a.x, a.y, a.z, a.w};
      #pragma unroll
      for (int j = 0; j < 4; ++j){
        aU[m].x = fmaf(av[j], wu[j].x, aU[m].x);
        aU[m].y = fmaf(av[j], wu[j].y, aU[m].y);
        aU[m].z = fmaf(av[j], wu[j].z, aU[m].z);
        aU[m].w = fmaf(av[j], wu[j].w, aU[m].w);
        aV[m].x = fmaf(av[j], wv[j].x, aV[m].x);
        aV[m].y = fmaf(av[j], wv[j].y, aV[m].y);
        aV[m].z = fmaf(av[j], wv[j].z, aV[m].z);
        aV[m].w = fmaf(av[j], wv[j].w, aV[m].w);
      }
    }
  }
  const float4 b = ((const float4*)biasU)[c4];
  #pragma unroll
  for (int m = 0; m < 8; ++m){
    const int r = row0 + m*8 + rg;
    if (r >= n) continue;
    float4 xu = aU[m];
    xu.x += b.x; xu.y += b.y; xu.z += b.z; xu.w += b.w;
    ushort4 pu;
    pu.x = f2bf(xu.x); pu.y = f2bf(xu.y); pu.z = f2bf(xu.z); pu.w = f2bf(xu.w);
    ((ushort4*)(outU + (size_t)r*HD))[c4] = pu;
    ushort4 pv;
    pv.x = f2bf(aV[m].x); pv.y = f2bf(aV[m].y); pv.z = f2bf(aV[m].z); pv.w = f2bf(aV[m].w);
    ((ushort4*)(outV + (size_t)r*HD))[c4] = pv;
  }
}

// ------------- fused mask+msg, 16-lane edge groups, 2-deep pipeline -------------
__global__ __launch_bounds__(256) void mask_msg_kernel(
    float* __restrict__ h,                  // in-place: read own row, write own row
    const ushort_t* __restrict__ U, const ushort_t* __restrict__ V,
    const ushort_t* __restrict__ hB,
    const int* __restrict__ srcS, const int* __restrict__ eidS,
    const int* __restrict__ row_start,
    const float* __restrict__ Wm2, const float* __restrict__ bm2,
    float* __restrict__ maskOut)            // nullptr except final layer
{
  const int v = blockIdx.x*4 + (threadIdx.x >> 6);
  const int lane = threadIdx.x & 63;
  const int g   = lane >> 4;                // edge group 0..3
  const int sub = lane & 15;                // lane in group
  const float4 wA = ((const float4*)Wm2)[sub*2];      // cols sub*8..+3
  const float4 wB = ((const float4*)Wm2)[sub*2+1];    // cols sub*8+4..+7
  const float b2 = bm2[0];
  const uint4 vv = ((const uint4*)(V + (size_t)v*HD))[sub];
  float a0=0.f,a1=0.f,a2=0.f,a3=0.f,a4=0.f,a5=0.f,a6=0.f,a7=0.f;
  const int beg = row_start[v], end = row_start[v+1];
  int idx = beg + g;
  uint4 uu = make_uint4(0,0,0,0), hh = make_uint4(0,0,0,0);
  int e0 = 0;
  if (idx < end){
    const int s = srcS[idx];
    if (maskOut) e0 = eidS[idx];
    uu = ((const uint4*)(U  + (size_t)s*HD))[sub];
    hh = ((const uint4*)(hB + (size_t)s*HD))[sub];
  }
  while (idx < end){
    // prefetch next edge for this group (2-deep pipeline)
    const int nidx = idx + 4;
    uint4 uuN = make_uint4(0,0,0,0), hhN = make_uint4(0,0,0,0);
    int eN = 0;
    if (nidx < end){
      const int sn = srcS[nidx];
      if (maskOut) eN = eidS[nidx];
      uuN = ((const uint4*)(U  + (size_t)sn*HD))[sub];
      hhN = ((const uint4*)(hB + (size_t)sn*HD))[sub];
    }
    // compute current edge
    float p;
    p = fmaxf(bflo(uu.x)+bflo(vv.x), 0.f) * wA.x;
    p = fmaf(fmaxf(bfhi(uu.x)+bfhi(vv.x), 0.f), wA.y, p);
    p = fmaf(fmaxf(bflo(uu.y)+bflo(vv.y), 0.f), wA.z, p);
    p = fmaf(fmaxf(bfhi(uu.y)+bfhi(vv.y), 0.f), wA.w, p);
    p = fmaf(fmaxf(bflo(uu.z)+bflo(vv.z), 0.f), wB.x, p);
    p = fmaf(fmaxf(bfhi(uu.z)+bfhi(vv.z), 0.f), wB.y, p);
    p = fmaf(fmaxf(bflo(uu.w)+bflo(vv.w), 0.f), wB.z, p);
    p = fmaf(fmaxf(bfhi(uu.w)+bfhi(vv.w), 0.f), wB.w, p);
    p += __shfl_xor(p, 1, 64);
    p += __shfl_xor(p, 2, 64);
    p += __shfl_xor(p, 4, 64);
    p += __shfl_xor(p, 8, 64);
    const float imp = sigmoidf_(p + b2);
    const float mk  = sigmoidf_((imp - 0.4f) * 2.0f);
    if (maskOut != nullptr && sub == 0) maskOut[e0] = mk;
    a0 = fmaf(mk, bflo(hh.x), a0);
    a1 = fmaf(mk, bfhi(hh.x), a1);
    a2 = fmaf(mk, bflo(hh.y), a2);
    a3 = fmaf(mk, bfhi(hh.y), a3);
    a4 = fmaf(mk, bflo(hh.z), a4);
    a5 = fmaf(mk, bfhi(hh.z), a5);
    a6 = fmaf(mk, bflo(hh.w), a6);
    a7 = fmaf(mk, bfhi(hh.w), a7);
    uu = uuN; hh = hhN; e0 = eN; idx = nidx;
  }
  // cross-group combine (sum over the 4 groups)
  a0 += __shfl_xor(a0, 16, 64); a0 += __shfl_xor(a0, 32, 64);
  a1 += __shfl_xor(a1, 16, 64); a1 += __shfl_xor(a1, 32, 64);
  a2 += __shfl_xor(a2, 16, 64); a2 += __shfl_xor(a2, 32, 64);
  a3 += __shfl_xor(a3, 16, 64); a3 += __shfl_xor(a3, 32, 64);
  a4 += __shfl_xor(a4, 16, 64); a4 += __shfl_xor(a4, 32, 64);
  a5 += __shfl_xor(a5, 16, 64); a5 += __shfl_xor(a5, 32, 64);
  a6 += __shfl_xor(a6, 16, 64); a6 += __shfl_xor(a6, 32, 64);
  a7 += __shfl_xor(a7, 16, 64); a7 += __shfl_xor(a7, 32, 64);
  if (g == 0){
    float4* hrow = (float4*)(h + (size_t)v*HD);
    float4 x0 = hrow[sub*2];
    float4 x1 = hrow[sub*2+1];
    x0.x += a0; x0.y += a1; x0.z += a2; x0.w += a3;
    x1.x += a4; x1.y += a5; x1.z += a6; x1.w += a7;
    hrow[sub*2]   = x0;
    hrow[sub*2+1] = x1;
  }
}

// ---------------- predictor ----------------
__global__ __launch_bounds__(128) void pred_kernel(const float* __restrict__ h,
  const float* __restrict__ Wp1, const float* __restrict__ bp1,
  const float* __restrict__ Wp2, const float* __restrict__ bp2,
  float* __restrict__ out0)
{
  __shared__ float red[128];
  const int t = threadIdx.x;
  float s = bp1[t];
  for (int k = 0; k < HD; ++k) s = fmaf(h[k], Wp1[k*HD + t], s);
  s = fmaxf(s, 0.f) * Wp2[t];
  red[t] = s;
  __syncthreads();
  for (int off = 64; off > 0; off >>= 1){
    if (t < off) red[t] += red[t + off];
    __syncthreads();
  }
  if (t == 0) out0[0] = red[0] + bp2[0];
}

extern "C" void kernel_launch(void* const* d_in, const int* in_sizes, int n_in,
                              void* d_out, int out_size, void* d_ws, size_t ws_size,
                              hipStream_t stream)
{
  (void)out_size;
  float* fOut = (float*)d_out;
  float* predOut = fOut;               // f32[0]
  float* maskOut = fOut + 1;           // f32[1 .. 1+NE)
  float* hOut    = fOut + 1 + NE;      // f32[1+NE ..)

  // ---- env tripwire (clean since R5; kept) ----
  static const int expSizes[14] = {6400000,1200000,16384,128,49152,384,32768,128,128,1,
                                   16384,128,128,1};
  const size_t NEEDED = 87100000;
  float diag = 0.f;
  if (n_in != 14) diag = 900.f + (float)n_in;
  else {
    for (int i = 0; i < 14; ++i)
      if (in_sizes[i] != expSizes[i]){ diag = 200.f + 16.f*(float)i; break; }
  }
  if (diag == 0.f && ws_size < NEEDED) diag = 5000.f + (float)(ws_size >> 20);

  if (diag != 0.f){
    write_scalar_kernel<<<1, 1, 0, stream>>>(predOut, diag);
    return;
  }

  const float* nf   = (const float*)d_in[0];
  const void*  ei   = d_in[1];
  const float* Wemb = (const float*)d_in[2];
  const float* bemb = (const float*)d_in[3];
  const float* Wgnn = (const float*)d_in[4];
  const float* bgnn = (const float*)d_in[5];
  const float* Wm1  = (const float*)d_in[6];
  const float* bm1  = (const float*)d_in[7];
  const float* Wm2  = (const float*)d_in[8];
  const float* bm2  = (const float*)d_in[9];
  const float* Wp1  = (const float*)d_in[10];
  const float* bp1  = (const float*)d_in[11];
  const float* Wp2  = (const float*)d_in[12];
  const float* bp2  = (const float*)d_in[13];

  float* hA    = (float*)d_ws;                        // h f32 (in-place)          25.6MB
  float* tmpU  = hA   + (size_t)NN*HD;                // Ub bf16                   25.6MB
  float* Vbuf  = tmpU + (size_t)NN*HD;                // Vb bf16 + hB bf16         25.6MB
  float* srcSf = Vbuf + (size_t)NN*HD;                // srcS int                   2.4MB
  int* srcS    = (int*)srcSf;                         // NE
  int* row_start = srcS + NE;                         // NN+1
  int* cursor  = row_start + (NN + 1);                // NN
  int* counts  = cursor + NN;                         // NN
  int* eids    = counts + NN;                         // NE
  int* srcW    = eids + NE;                           // NE
  int* dstW    = srcW + NE;                           // NE
  int* flag    = dstW + NE;                           // 1
  int* partial = flag + 1;                            // NBLK
  int* bOff    = partial + NBLK;                      // NBLK

  ushort_t* Ub = (ushort_t*)tmpU;                     // bf16 U
  ushort_t* Vb = (ushort_t*)Vbuf;                     // bf16 V
  ushort_t* hB = (ushort_t*)Vbuf + (size_t)NN*HD;     // bf16 h shadow

  // --- decode edge_index + dst histogram ---
  hipMemsetAsync(flag, 0, sizeof(int), stream);
  hipMemsetAsync(counts, 0, NN*sizeof(int), stream);
  detect_kernel<<<DET_SAMPLES/256, 256, 0, stream>>>((const unsigned int*)ei, flag);
  extract_kernel<<<(NE + 255)/256, 256, 0, stream>>>(ei, flag, srcW, dstW, counts);

  // --- CSR: hierarchical exclusive scan + fill (with CSR-ordered src) ---
  scanA_kernel<<<NBLK, 256, 0, stream>>>(counts, partial);
  scanB_kernel<<<1, 256, 0, stream>>>(partial, bOff);
  scanC_kernel<<<NBLK, 256, 0, stream>>>(counts, bOff, row_start, cursor);
  fill_kernel<<<(NE + 255)/256, 256, 0, stream>>>(dstW, srcW, cursor, eids, srcS);

  // h = relu(nf@Wemb+bemb): f32 + bf16 shadow
  gemm_h<<<GGRID, 256, 0, stream>>>(nf, Wemb, bemb, hA, hB, NN, 1);

  for (int L = 0; L < 3; ++L){
    float* hnext = (L < 2) ? hA : hOut;               // h-gemm in-place for L<2
    ushort_t* hBnext = (L < 2) ? hB : nullptr;
    float* mOut = (L < 2) ? nullptr : maskOut;
    gemm_uv<<<GGRID, 256, 0, stream>>>(hA, Wm1, Wm1 + HD*HD, bm1, Ub, Vb, NN);
    mask_msg_kernel<<<NN/4, 256, 0, stream>>>(hA, Ub, Vb, hB, srcS, eids, row_start,
                                              Wm2, bm2, mOut);
    gemm_h<<<GGRID, 256, 0, stream>>>(hA, Wgnn + (size_t)L*HD*HD, bgnn + (size_t)L*HD,
                                      hnext, hBnext, NN, 1);
  }

  pred_kernel<<<1, 128, 0, stream>>>(hOut, Wp1, bp1, Wp2, bp2, predOut);
}

// Round 17
// 553.673 us; speedup vs baseline: 1.1629x; 1.1629x over previous
//
#include <hip/hip_runtime.h>
#include <hip/hip_bf16.h>

#define NN 50000
#define NE 600000
#define HD 128
#define DET_SAMPLES 65536
#define NBLK 196                     // ceil((NN+1)/256)
#define GROWS 64                     // rows per GEMM block
#define GGRID ((NN + GROWS - 1)/GROWS)

typedef unsigned short ushort_t;

__device__ __forceinline__ float sigmoidf_(float x){ return 1.f/(1.f+__expf(-x)); }

__device__ __forceinline__ ushort_t f2bf(float f){
  unsigned int u = __float_as_uint(f);
  unsigned int r = (u + 0x7FFFu + ((u >> 16) & 1u)) >> 16;   // RNE
  return (ushort_t)r;
}

__device__ __forceinline__ float bflo(unsigned u){ return __uint_as_float(u << 16); }
__device__ __forceinline__ float bfhi(unsigned u){ return __uint_as_float(u & 0xFFFF0000u); }

// ---------------- diagnostic scalar write (env tripwire) ----------------
__global__ void write_scalar_kernel(float* __restrict__ p, float v){ p[0] = v; }

// ---------------- edge_index dtype detect + decode (+ dst histogram) ----------------
__global__ void detect_kernel(const unsigned int* __restrict__ w, int* __restrict__ flag){
  int i = blockIdx.x*256 + threadIdx.x;           // [0, DET_SAMPLES)
  int z = (w[2*i + 1] == 0u) ? 1 : 0;
  atomicAdd(flag, z);
}

__global__ void extract_kernel(const void* __restrict__ ei, const int* __restrict__ flag,
                               int* __restrict__ srcW, int* __restrict__ dstW,
                               int* __restrict__ counts){
  const int e = blockIdx.x*256 + threadIdx.x;
  if (e >= NE) return;
  int s, d;
  if (*flag > (DET_SAMPLES/2)){
    const long long* p = (const long long*)ei;
    s = (int)p[e]; d = (int)p[NE + e];
  } else {
    const int* p = (const int*)ei;
    s = p[e]; d = p[NE + e];
  }
  srcW[e] = s; dstW[e] = d;
  atomicAdd(&counts[d], 1);
}

// ---------------- hierarchical exclusive scan of counts[NN] ----------------
__global__ __launch_bounds__(256) void scanA_kernel(const int* __restrict__ counts,
                                                    int* __restrict__ partial){
  __shared__ int s[256];
  const int t = threadIdx.x;
  const int idx = blockIdx.x*256 + t;
  s[t] = (idx < NN) ? counts[idx] : 0;
  __syncthreads();
  for (int off = 128; off > 0; off >>= 1){
    if (t < off) s[t] += s[t + off];
    __syncthreads();
  }
  if (t == 0) partial[blockIdx.x] = s[0];
}

__global__ __launch_bounds__(256) void scanB_kernel(const int* __restrict__ partial,
                                                    int* __restrict__ bOff){
  __shared__ int s[256];
  const int t = threadIdx.x;
  const int v = (t < NBLK) ? partial[t] : 0;
  s[t] = v;
  __syncthreads();
  for (int off = 1; off < 256; off <<= 1){
    int add = (t >= off) ? s[t - off] : 0;
    __syncthreads();
    s[t] += add;
    __syncthreads();
  }
  if (t < NBLK) bOff[t] = s[t] - v;        // exclusive
}

__global__ __launch_bounds__(256) void scanC_kernel(const int* __restrict__ counts,
    const int* __restrict__ bOff, int* __restrict__ row_start, int* __restrict__ cursor){
  __shared__ int s[256];
  const int t = threadIdx.x;
  const int idx = blockIdx.x*256 + t;
  const int c = (idx < NN) ? counts[idx] : 0;
  s[t] = c;
  __syncthreads();
  for (int off = 1; off < 256; off <<= 1){
    int add = (t >= off) ? s[t - off] : 0;
    __syncthreads();
    s[t] += add;
    __syncthreads();
  }
  const int excl = bOff[blockIdx.x] + s[t] - c;
  if (idx < NN){ row_start[idx] = excl; cursor[idx] = excl; }
  else if (idx == NN){ row_start[NN] = excl; }
}

// fill: also writes CSR-ordered src (srcS) so msg needs no eids->srcI indirection
__global__ void fill_kernel(const int* __restrict__ dstI, const int* __restrict__ srcI,
                            int* __restrict__ cursor, int* __restrict__ eids,
                            int* __restrict__ srcS){
  int e = blockIdx.x*256 + threadIdx.x;
  if (e < NE){
    int p = atomicAdd(&cursor[dstI[e]], 1);
    eids[p] = e;
    srcS[p] = srcI[e];
  }
}

// ---------------- GEMM (single W): out = act(in @ W + bias) [R14 version] ----------
// W read from L2 (coalesced float4 per k); LDS holds only the 64-row input tile.
// Safe in-place (outF == in): block stages its rows before writing, writes only them.
__global__ __launch_bounds__(256) void gemm_h(const float* __restrict__ in,
    const float* __restrict__ W, const float* __restrict__ bias,
    float* __restrict__ outF, ushort_t* __restrict__ outB, int n, int doRelu)
{
  __shared__ float Is[GROWS*HD];                 // 32 KB
  const int t = threadIdx.x;
  const int row0 = blockIdx.x * GROWS;
  const float4* src = (const float4*)(in + (size_t)row0*HD);
  float4* dst4 = (float4*)Is;
  #pragma unroll
  for (int i = 0; i < 8; ++i){
    int idx = t + i*256;                         // 2048 float4
    float4 v = make_float4(0.f,0.f,0.f,0.f);
    if (row0 + (idx >> 5) < n) v = src[idx];
    dst4[idx] = v;
  }
  __syncthreads();
  const int c4 = t & 31;                         // float4 column
  const int rg = t >> 5;                         // 0..7; rows m*8+rg
  float4 acc[8];
  #pragma unroll
  for (int m = 0; m < 8; ++m) acc[m] = make_float4(0.f,0.f,0.f,0.f);
  #pragma unroll 4
  for (int k = 0; k < HD; ++k){
    const float4 w = ((const float4*)(W + (size_t)k*HD))[c4];
    #pragma unroll
    for (int m = 0; m < 8; ++m){
      const float a = Is[(m*8+rg)*HD + k];       // broadcast read
      acc[m].x = fmaf(a, w.x, acc[m].x);
      acc[m].y = fmaf(a, w.y, acc[m].y);
      acc[m].z = fmaf(a, w.z, acc[m].z);
      acc[m].w = fmaf(a, w.w, acc[m].w);
    }
  }
  float4 b = make_float4(0.f,0.f,0.f,0.f);
  if (bias) b = ((const float4*)bias)[c4];
  #pragma unroll
  for (int m = 0; m < 8; ++m){
    const int r = row0 + m*8 + rg;
    if (r >= n) continue;
    float4 x = acc[m];
    x.x += b.x; x.y += b.y; x.z += b.z; x.w += b.w;
    if (doRelu){
      x.x = fmaxf(x.x, 0.f); x.y = fmaxf(x.y, 0.f);
      x.z = fmaxf(x.z, 0.f); x.w = fmaxf(x.w, 0.f);
    }
    if (outF) ((float4*)(outF + (size_t)r*HD))[c4] = x;
    if (outB){
      ushort4 p;
      p.x = f2bf(x.x); p.y = f2bf(x.y); p.z = f2bf(x.z); p.w = f2bf(x.w);
      ((ushort4*)(outB + (size_t)r*HD))[c4] = p;
    }
  }
}

// ------- fused U/V GEMM: U = in@Wu + bu, V = in@Wv (both bf16 out) [R14 version] -----
__global__ __launch_bounds__(256) void gemm_uv(const float* __restrict__ in,
    const float* __restrict__ Wu, const float* __restrict__ Wv,
    const float* __restrict__ biasU,
    ushort_t* __restrict__ outU, ushort_t* __restrict__ outV, int n)
{
  __shared__ float Is[GROWS*HD];                 // 32 KB
  const int t = threadIdx.x;
  const int row0 = blockIdx.x * GROWS;
  const float4* src = (const float4*)(in + (size_t)row0*HD);
  float4* dst4 = (float4*)Is;
  #pragma unroll
  for (int i = 0; i < 8; ++i){
    int idx = t + i*256;
    float4 v = make_float4(0.f,0.f,0.f,0.f);
    if (row0 + (idx >> 5) < n) v = src[idx];
    dst4[idx] = v;
  }
  __syncthreads();
  const int c4 = t & 31;
  const int rg = t >> 5;
  float4 aU[8], aV[8];
  #pragma unroll
  for (int m = 0; m < 8; ++m){
    aU[m] = make_float4(0.f,0.f,0.f,0.f);
    aV[m] = make_float4(0.f,0.f,0.f,0.f);
  }
  #pragma unroll 2
  for (int k = 0; k < HD; ++k){
    const float4 wu = ((const float4*)(Wu + (size_t)k*HD))[c4];
    const float4 wv = ((const float4*)(Wv + (size_t)k*HD))[c4];
    #pragma unroll
    for (int m = 0; m < 8; ++m){
      const float a = Is[(m*8+rg)*HD + k];
      aU[m].x = fmaf(a, wu.x, aU[m].x);
      aU[m].y = fmaf(a, wu.y, aU[m].y);
      aU[m].z = fmaf(a, wu.z, aU[m].z);
      aU[m].w = fmaf(a, wu.w, aU[m].w);
      aV[m].x = fmaf(a, wv.x, aV[m].x);
      aV[m].y = fmaf(a, wv.y, aV[m].y);
      aV[m].z = fmaf(a, wv.z, aV[m].z);
      aV[m].w = fmaf(a, wv.w, aV[m].w);
    }
  }
  const float4 b = ((const float4*)biasU)[c4];
  #pragma unroll
  for (int m = 0; m < 8; ++m){
    const int r = row0 + m*8 + rg;
    if (r >= n) continue;
    float4 xu = aU[m];
    xu.x += b.x; xu.y += b.y; xu.z += b.z; xu.w += b.w;
    ushort4 pu;
    pu.x = f2bf(xu.x); pu.y = f2bf(xu.y); pu.z = f2bf(xu.z); pu.w = f2bf(xu.w);
    ((ushort4*)(outU + (size_t)r*HD))[c4] = pu;
    ushort4 pv;
    pv.x = f2bf(aV[m].x); pv.y = f2bf(aV[m].y); pv.z = f2bf(aV[m].z); pv.w = f2bf(aV[m].w);
    ((ushort4*)(outV + (size_t)r*HD))[c4] = pv;
  }
}

// ------------- fused mask+msg, 16-lane edge groups, 2-deep pipeline -------------
__global__ __launch_bounds__(256) void mask_msg_kernel(
    float* __restrict__ h,                  // in-place: read own row, write own row
    const ushort_t* __restrict__ U, const ushort_t* __restrict__ V,
    const ushort_t* __restrict__ hB,
    const int* __restrict__ srcS, const int* __restrict__ eidS,
    const int* __restrict__ row_start,
    const float* __restrict__ Wm2, const float* __restrict__ bm2,
    float* __restrict__ maskOut)            // nullptr except final layer
{
  const int v = blockIdx.x*4 + (threadIdx.x >> 6);
  const int lane = threadIdx.x & 63;
  const int g   = lane >> 4;                // edge group 0..3
  const int sub = lane & 15;                // lane in group
  const float4 wA = ((const float4*)Wm2)[sub*2];      // cols sub*8..+3
  const float4 wB = ((const float4*)Wm2)[sub*2+1];    // cols sub*8+4..+7
  const float b2 = bm2[0];
  const uint4 vv = ((const uint4*)(V + (size_t)v*HD))[sub];
  float a0=0.f,a1=0.f,a2=0.f,a3=0.f,a4=0.f,a5=0.f,a6=0.f,a7=0.f;
  const int beg = row_start[v], end = row_start[v+1];
  int idx = beg + g;
  uint4 uu = make_uint4(0,0,0,0), hh = make_uint4(0,0,0,0);
  int e0 = 0;
  if (idx < end){
    const int s = srcS[idx];
    if (maskOut) e0 = eidS[idx];
    uu = ((const uint4*)(U  + (size_t)s*HD))[sub];
    hh = ((const uint4*)(hB + (size_t)s*HD))[sub];
  }
  while (idx < end){
    // prefetch next edge for this group (2-deep pipeline)
    const int nidx = idx + 4;
    uint4 uuN = make_uint4(0,0,0,0), hhN = make_uint4(0,0,0,0);
    int eN = 0;
    if (nidx < end){
      const int sn = srcS[nidx];
      if (maskOut) eN = eidS[nidx];
      uuN = ((const uint4*)(U  + (size_t)sn*HD))[sub];
      hhN = ((const uint4*)(hB + (size_t)sn*HD))[sub];
    }
    // compute current edge
    float p;
    p = fmaxf(bflo(uu.x)+bflo(vv.x), 0.f) * wA.x;
    p = fmaf(fmaxf(bfhi(uu.x)+bfhi(vv.x), 0.f), wA.y, p);
    p = fmaf(fmaxf(bflo(uu.y)+bflo(vv.y), 0.f), wA.z, p);
    p = fmaf(fmaxf(bfhi(uu.y)+bfhi(vv.y), 0.f), wA.w, p);
    p = fmaf(fmaxf(bflo(uu.z)+bflo(vv.z), 0.f), wB.x, p);
    p = fmaf(fmaxf(bfhi(uu.z)+bfhi(vv.z), 0.f), wB.y, p);
    p = fmaf(fmaxf(bflo(uu.w)+bflo(vv.w), 0.f), wB.z, p);
    p = fmaf(fmaxf(bfhi(uu.w)+bfhi(vv.w), 0.f), wB.w, p);
    p += __shfl_xor(p, 1, 64);
    p += __shfl_xor(p, 2, 64);
    p += __shfl_xor(p, 4, 64);
    p += __shfl_xor(p, 8, 64);
    const float imp = sigmoidf_(p + b2);
    const float mk  = sigmoidf_((imp - 0.4f) * 2.0f);
    if (maskOut != nullptr && sub == 0) maskOut[e0] = mk;
    a0 = fmaf(mk, bflo(hh.x), a0);
    a1 = fmaf(mk, bfhi(hh.x), a1);
    a2 = fmaf(mk, bflo(hh.y), a2);
    a3 = fmaf(mk, bfhi(hh.y), a3);
    a4 = fmaf(mk, bflo(hh.z), a4);
    a5 = fmaf(mk, bfhi(hh.z), a5);
    a6 = fmaf(mk, bflo(hh.w), a6);
    a7 = fmaf(mk, bfhi(hh.w), a7);
    uu = uuN; hh = hhN; e0 = eN; idx = nidx;
  }
  // cross-group combine (sum over the 4 groups)
  a0 += __shfl_xor(a0, 16, 64); a0 += __shfl_xor(a0, 32, 64);
  a1 += __shfl_xor(a1, 16, 64); a1 += __shfl_xor(a1, 32, 64);
  a2 += __shfl_xor(a2, 16, 64); a2 += __shfl_xor(a2, 32, 64);
  a3 += __shfl_xor(a3, 16, 64); a3 += __shfl_xor(a3, 32, 64);
  a4 += __shfl_xor(a4, 16, 64); a4 += __shfl_xor(a4, 32, 64);
  a5 += __shfl_xor(a5, 16, 64); a5 += __shfl_xor(a5, 32, 64);
  a6 += __shfl_xor(a6, 16, 64); a6 += __shfl_xor(a6, 32, 64);
  a7 += __shfl_xor(a7, 16, 64); a7 += __shfl_xor(a7, 32, 64);
  if (g == 0){
    float4* hrow = (float4*)(h + (size_t)v*HD);
    float4 x0 = hrow[sub*2];
    float4 x1 = hrow[sub*2+1];
    x0.x += a0; x0.y += a1; x0.z += a2; x0.w += a3;
    x1.x += a4; x1.y += a5; x1.z += a6; x1.w += a7;
    hrow[sub*2]   = x0;
    hrow[sub*2+1] = x1;
  }
}

// ---------------- predictor ----------------
__global__ __launch_bounds__(128) void pred_kernel(const float* __restrict__ h,
  const float* __restrict__ Wp1, const float* __restrict__ bp1,
  const float* __restrict__ Wp2, const float* __restrict__ bp2,
  float* __restrict__ out0)
{
  __shared__ float red[128];
  const int t = threadIdx.x;
  float s = bp1[t];
  for (int k = 0; k < HD; ++k) s = fmaf(h[k], Wp1[k*HD + t], s);
  s = fmaxf(s, 0.f) * Wp2[t];
  red[t] = s;
  __syncthreads();
  for (int off = 64; off > 0; off >>= 1){
    if (t < off) red[t] += red[t + off];
    __syncthreads();
  }
  if (t == 0) out0[0] = red[0] + bp2[0];
}

extern "C" void kernel_launch(void* const* d_in, const int* in_sizes, int n_in,
                              void* d_out, int out_size, void* d_ws, size_t ws_size,
                              hipStream_t stream)
{
  (void)out_size;
  float* fOut = (float*)d_out;
  float* predOut = fOut;               // f32[0]
  float* maskOut = fOut + 1;           // f32[1 .. 1+NE)
  float* hOut    = fOut + 1 + NE;      // f32[1+NE ..)

  // ---- env tripwire (clean since R5; kept) ----
  static const int expSizes[14] = {6400000,1200000,16384,128,49152,384,32768,128,128,1,
                                   16384,128,128,1};
  const size_t NEEDED = 87100000;
  float diag = 0.f;
  if (n_in != 14) diag = 900.f + (float)n_in;
  else {
    for (int i = 0; i < 14; ++i)
      if (in_sizes[i] != expSizes[i]){ diag = 200.f + 16.f*(float)i; break; }
  }
  if (diag == 0.f && ws_size < NEEDED) diag = 5000.f + (float)(ws_size >> 20);

  if (diag != 0.f){
    write_scalar_kernel<<<1, 1, 0, stream>>>(predOut, diag);
    return;
  }

  const float* nf   = (const float*)d_in[0];
  const void*  ei   = d_in[1];
  const float* Wemb = (const float*)d_in[2];
  const float* bemb = (const float*)d_in[3];
  const float* Wgnn = (const float*)d_in[4];
  const float* bgnn = (const float*)d_in[5];
  const float* Wm1  = (const float*)d_in[6];
  const float* bm1  = (const float*)d_in[7];
  const float* Wm2  = (const float*)d_in[8];
  const float* bm2  = (const float*)d_in[9];
  const float* Wp1  = (const float*)d_in[10];
  const float* bp1  = (const float*)d_in[11];
  const float* Wp2  = (const float*)d_in[12];
  const float* bp2  = (const float*)d_in[13];

  float* hA    = (float*)d_ws;                        // h f32 (in-place)          25.6MB
  float* tmpU  = hA   + (size_t)NN*HD;                // Ub bf16                   25.6MB
  float* Vbuf  = tmpU + (size_t)NN*HD;                // Vb bf16 + hB bf16         25.6MB
  float* srcSf = Vbuf + (size_t)NN*HD;                // srcS int                   2.4MB
  int* srcS    = (int*)srcSf;                         // NE
  int* row_start = srcS + NE;                         // NN+1
  int* cursor  = row_start + (NN + 1);                // NN
  int* counts  = cursor + NN;                         // NN
  int* eids    = counts + NN;                         // NE
  int* srcW    = eids + NE;                           // NE
  int* dstW    = srcW + NE;                           // NE
  int* flag    = dstW + NE;                           // 1
  int* partial = flag + 1;                            // NBLK
  int* bOff    = partial + NBLK;                      // NBLK

  ushort_t* Ub = (ushort_t*)tmpU;                     // bf16 U
  ushort_t* Vb = (ushort_t*)Vbuf;                     // bf16 V
  ushort_t* hB = (ushort_t*)Vbuf + (size_t)NN*HD;     // bf16 h shadow

  // --- decode edge_index + dst histogram ---
  hipMemsetAsync(flag, 0, sizeof(int), stream);
  hipMemsetAsync(counts, 0, NN*sizeof(int), stream);
  detect_kernel<<<DET_SAMPLES/256, 256, 0, stream>>>((const unsigned int*)ei, flag);
  extract_kernel<<<(NE + 255)/256, 256, 0, stream>>>(ei, flag, srcW, dstW, counts);

  // --- CSR: hierarchical exclusive scan + fill (with CSR-ordered src) ---
  scanA_kernel<<<NBLK, 256, 0, stream>>>(counts, partial);
  scanB_kernel<<<1, 256, 0, stream>>>(partial, bOff);
  scanC_kernel<<<NBLK, 256, 0, stream>>>(counts, bOff, row_start, cursor);
  fill_kernel<<<(NE + 255)/256, 256, 0, stream>>>(dstW, srcW, cursor, eids, srcS);

  // h = relu(nf@Wemb+bemb): f32 + bf16 shadow
  gemm_h<<<GGRID, 256, 0, stream>>>(nf, Wemb, bemb, hA, hB, NN, 1);

  for (int L = 0; L < 3; ++L){
    float* hnext = (L < 2) ? hA : hOut;               // h-gemm in-place for L<2
    ushort_t* hBnext = (L < 2) ? hB : nullptr;
    float* mOut = (L < 2) ? nullptr : maskOut;
    gemm_uv<<<GGRID, 256, 0, stream>>>(hA, Wm1, Wm1 + HD*HD, bm1, Ub, Vb, NN);
    mask_msg_kernel<<<NN/4, 256, 0, stream>>>(hA, Ub, Vb, hB, srcS, eids, row_start,
                                              Wm2, bm2, mOut);
    gemm_h<<<GGRID, 256, 0, stream>>>(hA, Wgnn + (size_t)L*HD*HD, bgnn + (size_t)L*HD,
                                      hnext, hBnext, NN, 1);
  }

  pred_kernel<<<1, 128, 0, stream>>>(hOut, Wp1, bp1, Wp2, bp2, predOut);
}

// Round 18
// 521.268 us; speedup vs baseline: 1.2352x; 1.0622x over previous
//
#include <hip/hip_runtime.h>
#include <hip/hip_bf16.h>

#define NN 50000
#define NE 600000
#define HD 128
#define DET_SAMPLES 65536
#define NBLK 196                     // ceil((NN+1)/256)
#define GROWS 64                     // rows per GEMM block (4 waves x 16)
#define GGRID ((NN + GROWS - 1)/GROWS)

typedef unsigned short ushort_t;
typedef __attribute__((ext_vector_type(8))) short short8v;   // 8 bf16 (4 VGPRs)
typedef __attribute__((ext_vector_type(4))) float f32x4;

__device__ __forceinline__ float sigmoidf_(float x){ return 1.f/(1.f+__expf(-x)); }

__device__ __forceinline__ ushort_t f2bf(float f){
  unsigned int u = __float_as_uint(f);
  unsigned int r = (u + 0x7FFFu + ((u >> 16) & 1u)) >> 16;   // RNE
  return (ushort_t)r;
}

__device__ __forceinline__ float bflo(unsigned u){ return __uint_as_float(u << 16); }
__device__ __forceinline__ float bfhi(unsigned u){ return __uint_as_float(u & 0xFFFF0000u); }

// ---------------- diagnostic scalar write (env tripwire) ----------------
__global__ void write_scalar_kernel(float* __restrict__ p, float v){ p[0] = v; }

// ---------------- edge_index dtype detect + decode (+ dst histogram) ----------------
__global__ void detect_kernel(const unsigned int* __restrict__ w, int* __restrict__ flag){
  int i = blockIdx.x*256 + threadIdx.x;           // [0, DET_SAMPLES)
  int z = (w[2*i + 1] == 0u) ? 1 : 0;
  atomicAdd(flag, z);
}

__global__ void extract_kernel(const void* __restrict__ ei, const int* __restrict__ flag,
                               int* __restrict__ srcW, int* __restrict__ dstW,
                               int* __restrict__ counts){
  const int e = blockIdx.x*256 + threadIdx.x;
  if (e >= NE) return;
  int s, d;
  if (*flag > (DET_SAMPLES/2)){
    const long long* p = (const long long*)ei;
    s = (int)p[e]; d = (int)p[NE + e];
  } else {
    const int* p = (const int*)ei;
    s = p[e]; d = p[NE + e];
  }
  srcW[e] = s; dstW[e] = d;
  atomicAdd(&counts[d], 1);
}

// ---------------- hierarchical exclusive scan of counts[NN] ----------------
__global__ __launch_bounds__(256) void scanA_kernel(const int* __restrict__ counts,
                                                    int* __restrict__ partial){
  __shared__ int s[256];
  const int t = threadIdx.x;
  const int idx = blockIdx.x*256 + t;
  s[t] = (idx < NN) ? counts[idx] : 0;
  __syncthreads();
  for (int off = 128; off > 0; off >>= 1){
    if (t < off) s[t] += s[t + off];
    __syncthreads();
  }
  if (t == 0) partial[blockIdx.x] = s[0];
}

__global__ __launch_bounds__(256) void scanB_kernel(const int* __restrict__ partial,
                                                    int* __restrict__ bOff){
  __shared__ int s[256];
  const int t = threadIdx.x;
  const int v = (t < NBLK) ? partial[t] : 0;
  s[t] = v;
  __syncthreads();
  for (int off = 1; off < 256; off <<= 1){
    int add = (t >= off) ? s[t - off] : 0;
    __syncthreads();
    s[t] += add;
    __syncthreads();
  }
  if (t < NBLK) bOff[t] = s[t] - v;        // exclusive
}

__global__ __launch_bounds__(256) void scanC_kernel(const int* __restrict__ counts,
    const int* __restrict__ bOff, int* __restrict__ row_start, int* __restrict__ cursor){
  __shared__ int s[256];
  const int t = threadIdx.x;
  const int idx = blockIdx.x*256 + t;
  const int c = (idx < NN) ? counts[idx] : 0;
  s[t] = c;
  __syncthreads();
  for (int off = 1; off < 256; off <<= 1){
    int add = (t >= off) ? s[t - off] : 0;
    __syncthreads();
    s[t] += add;
    __syncthreads();
  }
  const int excl = bOff[blockIdx.x] + s[t] - c;
  if (idx < NN){ row_start[idx] = excl; cursor[idx] = excl; }
  else if (idx == NN){ row_start[NN] = excl; }
}

// fill: also writes CSR-ordered src (srcS) so msg needs no eids->srcI indirection
__global__ void fill_kernel(const int* __restrict__ dstI, const int* __restrict__ srcI,
                            int* __restrict__ cursor, int* __restrict__ eids,
                            int* __restrict__ srcS){
  int e = blockIdx.x*256 + threadIdx.x;
  if (e < NE){
    int p = atomicAdd(&cursor[dstI[e]], 1);
    eids[p] = e;
    srcS[p] = srcI[e];
  }
}

// ---------------- weight convert+transpose: Wt[n][k] = bf16(W[k][n]) --------------
__global__ __launch_bounds__(256) void wcvt_kernel(const float* __restrict__ W,
                                                   ushort_t* __restrict__ Wt){
  const int idx = blockIdx.x*256 + threadIdx.x;   // 16384
  const int k = idx >> 7, n = idx & 127;
  Wt[n*HD + k] = f2bf(W[idx]);
}

// ---------------- MFMA GEMM: out = act(bf16(in) @ Wt^T + bias) ----------------
// Per wave: 16 rows x 128 cols; A read f32->bf16 in-register; B from bf16 Wt[n][k] (L2).
// In-place safe (outF==in): all A reads feed acc before epilogue writes (same wave rows).
__global__ __launch_bounds__(256) void gemm_h_mfma(const float* __restrict__ in,
    const ushort_t* __restrict__ Wt, const float* __restrict__ bias,
    float* __restrict__ outF, ushort_t* __restrict__ outB, int n, int doRelu)
{
  const int wid  = threadIdx.x >> 6;
  const int lane = threadIdx.x & 63;
  const int fr = lane & 15;
  const int fq = lane >> 4;
  const int row0 = blockIdx.x*GROWS + wid*16;
  const int arow = row0 + fr;
  const bool rowok = (arow < n);
  f32x4 acc[8];
  #pragma unroll
  for (int tc = 0; tc < 8; ++tc) acc[tc] = (f32x4)0.0f;
  #pragma unroll
  for (int ks = 0; ks < 4; ++ks){
    const int k0 = ks*32 + fq*8;
    short8v af = (short8v)0;
    if (rowok){
      const float4 a0 = *(const float4*)(in + (size_t)arow*HD + k0);
      const float4 a1 = *(const float4*)(in + (size_t)arow*HD + k0 + 4);
      af[0]=(short)f2bf(a0.x); af[1]=(short)f2bf(a0.y);
      af[2]=(short)f2bf(a0.z); af[3]=(short)f2bf(a0.w);
      af[4]=(short)f2bf(a1.x); af[5]=(short)f2bf(a1.y);
      af[6]=(short)f2bf(a1.z); af[7]=(short)f2bf(a1.w);
    }
    #pragma unroll
    for (int tc = 0; tc < 8; ++tc){
      const short8v bf = *(const short8v*)(Wt + (size_t)(tc*16 + fr)*HD + k0);
      acc[tc] = __builtin_amdgcn_mfma_f32_16x16x32_bf16(af, bf, acc[tc], 0, 0, 0);
    }
  }
  #pragma unroll
  for (int tc = 0; tc < 8; ++tc){
    const int col = tc*16 + fr;
    const float b = bias ? bias[col] : 0.f;
    #pragma unroll
    for (int j = 0; j < 4; ++j){
      const int r = row0 + fq*4 + j;
      if (r >= n) continue;
      float x = acc[tc][j] + b;
      if (doRelu) x = fmaxf(x, 0.f);
      if (outF) outF[(size_t)r*HD + col] = x;
      if (outB) outB[(size_t)r*HD + col] = f2bf(x);
    }
  }
}

// ---------------- fused MFMA U/V GEMM: U = in@WtU^T + bu, V = in@WtV^T -------------
__global__ __launch_bounds__(256) void gemm_uv_mfma(const float* __restrict__ in,
    const ushort_t* __restrict__ WtU, const ushort_t* __restrict__ WtV,
    const float* __restrict__ biasU,
    ushort_t* __restrict__ outU, ushort_t* __restrict__ outV, int n)
{
  const int wid  = threadIdx.x >> 6;
  const int lane = threadIdx.x & 63;
  const int fr = lane & 15;
  const int fq = lane >> 4;
  const int row0 = blockIdx.x*GROWS + wid*16;
  const int arow = row0 + fr;
  const bool rowok = (arow < n);
  f32x4 aU[8], aV[8];
  #pragma unroll
  for (int tc = 0; tc < 8; ++tc){ aU[tc] = (f32x4)0.0f; aV[tc] = (f32x4)0.0f; }
  #pragma unroll
  for (int ks = 0; ks < 4; ++ks){
    const int k0 = ks*32 + fq*8;
    short8v af = (short8v)0;
    if (rowok){
      const float4 a0 = *(const float4*)(in + (size_t)arow*HD + k0);
      const float4 a1 = *(const float4*)(in + (size_t)arow*HD + k0 + 4);
      af[0]=(short)f2bf(a0.x); af[1]=(short)f2bf(a0.y);
      af[2]=(short)f2bf(a0.z); af[3]=(short)f2bf(a0.w);
      af[4]=(short)f2bf(a1.x); af[5]=(short)f2bf(a1.y);
      af[6]=(short)f2bf(a1.z); af[7]=(short)f2bf(a1.w);
    }
    #pragma unroll
    for (int tc = 0; tc < 8; ++tc){
      const short8v bu = *(const short8v*)(WtU + (size_t)(tc*16 + fr)*HD + k0);
      aU[tc] = __builtin_amdgcn_mfma_f32_16x16x32_bf16(af, bu, aU[tc], 0, 0, 0);
      const short8v bv = *(const short8v*)(WtV + (size_t)(tc*16 + fr)*HD + k0);
      aV[tc] = __builtin_amdgcn_mfma_f32_16x16x32_bf16(af, bv, aV[tc], 0, 0, 0);
    }
  }
  #pragma unroll
  for (int tc = 0; tc < 8; ++tc){
    const int col = tc*16 + fr;
    const float b = biasU[col];
    #pragma unroll
    for (int j = 0; j < 4; ++j){
      const int r = row0 + fq*4 + j;
      if (r >= n) continue;
      outU[(size_t)r*HD + col] = f2bf(aU[tc][j] + b);
      outV[(size_t)r*HD + col] = f2bf(aV[tc][j]);
    }
  }
}

// ------------- fused mask+msg, 16-lane edge groups, 2-deep pipeline -------------
__global__ __launch_bounds__(256) void mask_msg_kernel(
    float* __restrict__ h,                  // in-place: read own row, write own row
    const ushort_t* __restrict__ U, const ushort_t* __restrict__ V,
    const ushort_t* __restrict__ hB,
    const int* __restrict__ srcS, const int* __restrict__ eidS,
    const int* __restrict__ row_start,
    const float* __restrict__ Wm2, const float* __restrict__ bm2,
    float* __restrict__ maskOut)            // nullptr except final layer
{
  const int v = blockIdx.x*4 + (threadIdx.x >> 6);
  const int lane = threadIdx.x & 63;
  const int g   = lane >> 4;                // edge group 0..3
  const int sub = lane & 15;                // lane in group
  const float4 wA = ((const float4*)Wm2)[sub*2];      // cols sub*8..+3
  const float4 wB = ((const float4*)Wm2)[sub*2+1];    // cols sub*8+4..+7
  const float b2 = bm2[0];
  const uint4 vv = ((const uint4*)(V + (size_t)v*HD))[sub];
  float a0=0.f,a1=0.f,a2=0.f,a3=0.f,a4=0.f,a5=0.f,a6=0.f,a7=0.f;
  const int beg = row_start[v], end = row_start[v+1];
  int idx = beg + g;
  uint4 uu = make_uint4(0,0,0,0), hh = make_uint4(0,0,0,0);
  int e0 = 0;
  if (idx < end){
    const int s = srcS[idx];
    if (maskOut) e0 = eidS[idx];
    uu = ((const uint4*)(U  + (size_t)s*HD))[sub];
    hh = ((const uint4*)(hB + (size_t)s*HD))[sub];
  }
  while (idx < end){
    const int nidx = idx + 4;
    uint4 uuN = make_uint4(0,0,0,0), hhN = make_uint4(0,0,0,0);
    int eN = 0;
    if (nidx < end){
      const int sn = srcS[nidx];
      if (maskOut) eN = eidS[nidx];
      uuN = ((const uint4*)(U  + (size_t)sn*HD))[sub];
      hhN = ((const uint4*)(hB + (size_t)sn*HD))[sub];
    }
    float p;
    p = fmaxf(bflo(uu.x)+bflo(vv.x), 0.f) * wA.x;
    p = fmaf(fmaxf(bfhi(uu.x)+bfhi(vv.x), 0.f), wA.y, p);
    p = fmaf(fmaxf(bflo(uu.y)+bflo(vv.y), 0.f), wA.z, p);
    p = fmaf(fmaxf(bfhi(uu.y)+bfhi(vv.y), 0.f), wA.w, p);
    p = fmaf(fmaxf(bflo(uu.z)+bflo(vv.z), 0.f), wB.x, p);
    p = fmaf(fmaxf(bfhi(uu.z)+bfhi(vv.z), 0.f), wB.y, p);
    p = fmaf(fmaxf(bflo(uu.w)+bflo(vv.w), 0.f), wB.z, p);
    p = fmaf(fmaxf(bfhi(uu.w)+bfhi(vv.w), 0.f), wB.w, p);
    p += __shfl_xor(p, 1, 64);
    p += __shfl_xor(p, 2, 64);
    p += __shfl_xor(p, 4, 64);
    p += __shfl_xor(p, 8, 64);
    const float imp = sigmoidf_(p + b2);
    const float mk  = sigmoidf_((imp - 0.4f) * 2.0f);
    if (maskOut != nullptr && sub == 0) maskOut[e0] = mk;
    a0 = fmaf(mk, bflo(hh.x), a0);
    a1 = fmaf(mk, bfhi(hh.x), a1);
    a2 = fmaf(mk, bflo(hh.y), a2);
    a3 = fmaf(mk, bfhi(hh.y), a3);
    a4 = fmaf(mk, bflo(hh.z), a4);
    a5 = fmaf(mk, bfhi(hh.z), a5);
    a6 = fmaf(mk, bflo(hh.w), a6);
    a7 = fmaf(mk, bfhi(hh.w), a7);
    uu = uuN; hh = hhN; e0 = eN; idx = nidx;
  }
  a0 += __shfl_xor(a0, 16, 64); a0 += __shfl_xor(a0, 32, 64);
  a1 += __shfl_xor(a1, 16, 64); a1 += __shfl_xor(a1, 32, 64);
  a2 += __shfl_xor(a2, 16, 64); a2 += __shfl_xor(a2, 32, 64);
  a3 += __shfl_xor(a3, 16, 64); a3 += __shfl_xor(a3, 32, 64);
  a4 += __shfl_xor(a4, 16, 64); a4 += __shfl_xor(a4, 32, 64);
  a5 += __shfl_xor(a5, 16, 64); a5 += __shfl_xor(a5, 32, 64);
  a6 += __shfl_xor(a6, 16, 64); a6 += __shfl_xor(a6, 32, 64);
  a7 += __shfl_xor(a7, 16, 64); a7 += __shfl_xor(a7, 32, 64);
  if (g == 0){
    float4* hrow = (float4*)(h + (size_t)v*HD);
    float4 x0 = hrow[sub*2];
    float4 x1 = hrow[sub*2+1];
    x0.x += a0; x0.y += a1; x0.z += a2; x0.w += a3;
    x1.x += a4; x1.y += a5; x1.z += a6; x1.w += a7;
    hrow[sub*2]   = x0;
    hrow[sub*2+1] = x1;
  }
}

// ---------------- predictor ----------------
__global__ __launch_bounds__(128) void pred_kernel(const float* __restrict__ h,
  const float* __restrict__ Wp1, const float* __restrict__ bp1,
  const float* __restrict__ Wp2, const float* __restrict__ bp2,
  float* __restrict__ out0)
{
  __shared__ float red[128];
  const int t = threadIdx.x;
  float s = bp1[t];
  for (int k = 0; k < HD; ++k) s = fmaf(h[k], Wp1[k*HD + t], s);
  s = fmaxf(s, 0.f) * Wp2[t];
  red[t] = s;
  __syncthreads();
  for (int off = 64; off > 0; off >>= 1){
    if (t < off) red[t] += red[t + off];
    __syncthreads();
  }
  if (t == 0) out0[0] = red[0] + bp2[0];
}

extern "C" void kernel_launch(void* const* d_in, const int* in_sizes, int n_in,
                              void* d_out, int out_size, void* d_ws, size_t ws_size,
                              hipStream_t stream)
{
  (void)out_size;
  float* fOut = (float*)d_out;
  float* predOut = fOut;               // f32[0]
  float* maskOut = fOut + 1;           // f32[1 .. 1+NE)
  float* hOut    = fOut + 1 + NE;      // f32[1+NE ..)

  // ---- env tripwire (clean since R5; kept) ----
  static const int expSizes[14] = {6400000,1200000,16384,128,49152,384,32768,128,128,1,
                                   16384,128,128,1};
  const size_t NEEDED = 87100000;
  float diag = 0.f;
  if (n_in != 14) diag = 900.f + (float)n_in;
  else {
    for (int i = 0; i < 14; ++i)
      if (in_sizes[i] != expSizes[i]){ diag = 200.f + 16.f*(float)i; break; }
  }
  if (diag == 0.f && ws_size < NEEDED) diag = 5000.f + (float)(ws_size >> 20);

  if (diag != 0.f){
    write_scalar_kernel<<<1, 1, 0, stream>>>(predOut, diag);
    return;
  }

  const float* nf   = (const float*)d_in[0];
  const void*  ei   = d_in[1];
  const float* Wemb = (const float*)d_in[2];
  const float* bemb = (const float*)d_in[3];
  const float* Wgnn = (const float*)d_in[4];
  const float* bgnn = (const float*)d_in[5];
  const float* Wm1  = (const float*)d_in[6];
  const float* bm1  = (const float*)d_in[7];
  const float* Wm2  = (const float*)d_in[8];
  const float* bm2  = (const float*)d_in[9];
  const float* Wp1  = (const float*)d_in[10];
  const float* bp1  = (const float*)d_in[11];
  const float* Wp2  = (const float*)d_in[12];
  const float* bp2  = (const float*)d_in[13];

  float* hA    = (float*)d_ws;                        // h f32 (in-place)          25.6MB
  float* tmpU  = hA   + (size_t)NN*HD;                // Ub bf16                   25.6MB
  float* Vbuf  = tmpU + (size_t)NN*HD;                // Vb bf16 + hB bf16         25.6MB
  float* srcSf = Vbuf + (size_t)NN*HD;                // srcS int                   2.4MB
  int* srcS    = (int*)srcSf;                         // NE
  int* row_start = srcS + NE;                         // NN+1
  int* cursor  = row_start + (NN + 1);                // NN (reused for Wt after fill)
  int* counts  = cursor + NN;                         // NN
  int* eids    = counts + NN;                         // NE
  int* srcW    = eids + NE;                           // NE
  int* dstW    = srcW + NE;                           // NE
  int* flag    = dstW + NE;                           // 1
  int* partial = flag + 1;                            // NBLK
  int* bOff    = partial + NBLK;                      // NBLK

  ushort_t* Ub = (ushort_t*)tmpU;                     // bf16 U
  ushort_t* Vb = (ushort_t*)Vbuf;                     // bf16 V
  ushort_t* hB = (ushort_t*)Vbuf + (size_t)NN*HD;     // bf16 h shadow

  // bf16 transposed weights live in the cursor region (dead after fill_kernel):
  // 6 x 16384 ushort = 196,608 B <= 200,000 B
  ushort_t* WtAll = (ushort_t*)cursor;
  ushort_t* WtEmb = WtAll;
  ushort_t* WtG0  = WtAll + 1*16384;
  ushort_t* WtG1  = WtAll + 2*16384;
  ushort_t* WtG2  = WtAll + 3*16384;
  ushort_t* WtU   = WtAll + 4*16384;
  ushort_t* WtV   = WtAll + 5*16384;

  // --- decode edge_index + dst histogram ---
  hipMemsetAsync(flag, 0, sizeof(int), stream);
  hipMemsetAsync(counts, 0, NN*sizeof(int), stream);
  detect_kernel<<<DET_SAMPLES/256, 256, 0, stream>>>((const unsigned int*)ei, flag);
  extract_kernel<<<(NE + 255)/256, 256, 0, stream>>>(ei, flag, srcW, dstW, counts);

  // --- CSR: hierarchical exclusive scan + fill (with CSR-ordered src) ---
  scanA_kernel<<<NBLK, 256, 0, stream>>>(counts, partial);
  scanB_kernel<<<1, 256, 0, stream>>>(partial, bOff);
  scanC_kernel<<<NBLK, 256, 0, stream>>>(counts, bOff, row_start, cursor);
  fill_kernel<<<(NE + 255)/256, 256, 0, stream>>>(dstW, srcW, cursor, eids, srcS);

  // --- weight convert+transpose (after fill: cursor region is dead) ---
  wcvt_kernel<<<64, 256, 0, stream>>>(Wemb,            WtEmb);
  wcvt_kernel<<<64, 256, 0, stream>>>(Wgnn,            WtG0);
  wcvt_kernel<<<64, 256, 0, stream>>>(Wgnn + 16384,    WtG1);
  wcvt_kernel<<<64, 256, 0, stream>>>(Wgnn + 32768,    WtG2);
  wcvt_kernel<<<64, 256, 0, stream>>>(Wm1,             WtU);
  wcvt_kernel<<<64, 256, 0, stream>>>(Wm1 + 16384,     WtV);

  // h = relu(nf@Wemb+bemb): f32 + bf16 shadow (MFMA)
  gemm_h_mfma<<<GGRID, 256, 0, stream>>>(nf, WtEmb, bemb, hA, hB, NN, 1);

  const ushort_t* WtG[3] = {WtG0, WtG1, WtG2};
  for (int L = 0; L < 3; ++L){
    float* hnext = (L < 2) ? hA : hOut;               // h-gemm in-place for L<2
    ushort_t* hBnext = (L < 2) ? hB : nullptr;
    float* mOut = (L < 2) ? nullptr : maskOut;
    gemm_uv_mfma<<<GGRID, 256, 0, stream>>>(hA, WtU, WtV, bm1, Ub, Vb, NN);
    mask_msg_kernel<<<NN/4, 256, 0, stream>>>(hA, Ub, Vb, hB, srcS, eids, row_start,
                                              Wm2, bm2, mOut);
    gemm_h_mfma<<<GGRID, 256, 0, stream>>>(hA, WtG[L], bgnn + (size_t)L*HD,
                                           hnext, hBnext, NN, 1);
  }

  pred_kernel<<<1, 128, 0, stream>>>(hOut, Wp1, bp1, Wp2, bp2, predOut);
}

// Round 19
// 506.302 us; speedup vs baseline: 1.2717x; 1.0296x over previous
//
#include <hip/hip_runtime.h>
#include <hip/hip_bf16.h>

#define NN 50000
#define NE 600000
#define HD 128
#define DET_SAMPLES 65536
#define NBLK 196                     // ceil((NN+1)/256)
#define GROWS 64                     // rows per GEMM block (4 waves x 16)
#define GGRID ((NN + GROWS - 1)/GROWS)

typedef unsigned short ushort_t;
typedef __attribute__((ext_vector_type(8))) short short8v;   // 8 bf16 (4 VGPRs)
typedef __attribute__((ext_vector_type(4))) float f32x4;

__device__ __forceinline__ float sigmoidf_(float x){ return 1.f/(1.f+__expf(-x)); }

__device__ __forceinline__ ushort_t f2bf(float f){
  unsigned int u = __float_as_uint(f);
  unsigned int r = (u + 0x7FFFu + ((u >> 16) & 1u)) >> 16;   // RNE
  return (ushort_t)r;
}

__device__ __forceinline__ float bflo(unsigned u){ return __uint_as_float(u << 16); }
__device__ __forceinline__ float bfhi(unsigned u){ return __uint_as_float(u & 0xFFFF0000u); }

// ---------------- diagnostic scalar write (env tripwire) ----------------
__global__ void write_scalar_kernel(float* __restrict__ p, float v){ p[0] = v; }

// ---------------- edge_index dtype detect + decode (+ dst histogram) ----------------
__global__ void detect_kernel(const unsigned int* __restrict__ w, int* __restrict__ flag){
  int i = blockIdx.x*256 + threadIdx.x;           // [0, DET_SAMPLES)
  int z = (w[2*i + 1] == 0u) ? 1 : 0;
  atomicAdd(flag, z);
}

__global__ void extract_kernel(const void* __restrict__ ei, const int* __restrict__ flag,
                               int* __restrict__ srcW, int* __restrict__ dstW,
                               int* __restrict__ counts){
  const int e = blockIdx.x*256 + threadIdx.x;
  if (e >= NE) return;
  int s, d;
  if (*flag > (DET_SAMPLES/2)){
    const long long* p = (const long long*)ei;
    s = (int)p[e]; d = (int)p[NE + e];
  } else {
    const int* p = (const int*)ei;
    s = p[e]; d = p[NE + e];
  }
  srcW[e] = s; dstW[e] = d;
  atomicAdd(&counts[d], 1);
}

// ---------------- hierarchical exclusive scan of counts[NN] ----------------
__global__ __launch_bounds__(256) void scanA_kernel(const int* __restrict__ counts,
                                                    int* __restrict__ partial){
  __shared__ int s[256];
  const int t = threadIdx.x;
  const int idx = blockIdx.x*256 + t;
  s[t] = (idx < NN) ? counts[idx] : 0;
  __syncthreads();
  for (int off = 128; off > 0; off >>= 1){
    if (t < off) s[t] += s[t + off];
    __syncthreads();
  }
  if (t == 0) partial[blockIdx.x] = s[0];
}

__global__ __launch_bounds__(256) void scanB_kernel(const int* __restrict__ partial,
                                                    int* __restrict__ bOff){
  __shared__ int s[256];
  const int t = threadIdx.x;
  const int v = (t < NBLK) ? partial[t] : 0;
  s[t] = v;
  __syncthreads();
  for (int off = 1; off < 256; off <<= 1){
    int add = (t >= off) ? s[t - off] : 0;
    __syncthreads();
    s[t] += add;
    __syncthreads();
  }
  if (t < NBLK) bOff[t] = s[t] - v;        // exclusive
}

__global__ __launch_bounds__(256) void scanC_kernel(const int* __restrict__ counts,
    const int* __restrict__ bOff, int* __restrict__ row_start, int* __restrict__ cursor){
  __shared__ int s[256];
  const int t = threadIdx.x;
  const int idx = blockIdx.x*256 + t;
  const int c = (idx < NN) ? counts[idx] : 0;
  s[t] = c;
  __syncthreads();
  for (int off = 1; off < 256; off <<= 1){
    int add = (t >= off) ? s[t - off] : 0;
    __syncthreads();
    s[t] += add;
    __syncthreads();
  }
  const int excl = bOff[blockIdx.x] + s[t] - c;
  if (idx < NN){ row_start[idx] = excl; cursor[idx] = excl; }
  else if (idx == NN){ row_start[NN] = excl; }
}

// fill: also writes CSR-ordered src (srcS) so msg needs no eids->srcI indirection
__global__ void fill_kernel(const int* __restrict__ dstI, const int* __restrict__ srcI,
                            int* __restrict__ cursor, int* __restrict__ eids,
                            int* __restrict__ srcS){
  int e = blockIdx.x*256 + threadIdx.x;
  if (e < NE){
    int p = atomicAdd(&cursor[dstI[e]], 1);
    eids[p] = e;
    srcS[p] = srcI[e];
  }
}

// ------- weight convert+transpose, all 6 matrices: Wt[n][k] = bf16(W[k][n]) --------
__global__ __launch_bounds__(256) void wcvt_all_kernel(const float* __restrict__ Wemb,
    const float* __restrict__ Wgnn, const float* __restrict__ Wm1,
    ushort_t* __restrict__ WtAll){
  const int idx = blockIdx.x*256 + threadIdx.x;   // 6*16384
  const int m = idx >> 14;                        // 0..5
  const int r = idx & 16383;
  const int k = r >> 7, n = r & 127;
  const float* W = (m == 0) ? Wemb : (m <= 3) ? (Wgnn + (size_t)(m-1)*16384)
                                              : (Wm1  + (size_t)(m-4)*16384);
  WtAll[(size_t)m*16384 + n*HD + k] = f2bf(W[r]);
}

// ---------------- MFMA GEMM, f32 A (embedding only) ----------------
__global__ __launch_bounds__(256) void gemm_h_mfma(const float* __restrict__ in,
    const ushort_t* __restrict__ Wt, const float* __restrict__ bias,
    float* __restrict__ outF, ushort_t* __restrict__ outB, int n, int doRelu)
{
  const int wid  = threadIdx.x >> 6;
  const int lane = threadIdx.x & 63;
  const int fr = lane & 15;
  const int fq = lane >> 4;
  const int row0 = blockIdx.x*GROWS + wid*16;
  const int arow = row0 + fr;
  const bool rowok = (arow < n);
  f32x4 acc[8];
  #pragma unroll
  for (int tc = 0; tc < 8; ++tc) acc[tc] = (f32x4)0.0f;
  #pragma unroll
  for (int ks = 0; ks < 4; ++ks){
    const int k0 = ks*32 + fq*8;
    short8v af = (short8v)0;
    if (rowok){
      const float4 a0 = *(const float4*)(in + (size_t)arow*HD + k0);
      const float4 a1 = *(const float4*)(in + (size_t)arow*HD + k0 + 4);
      af[0]=(short)f2bf(a0.x); af[1]=(short)f2bf(a0.y);
      af[2]=(short)f2bf(a0.z); af[3]=(short)f2bf(a0.w);
      af[4]=(short)f2bf(a1.x); af[5]=(short)f2bf(a1.y);
      af[6]=(short)f2bf(a1.z); af[7]=(short)f2bf(a1.w);
    }
    #pragma unroll
    for (int tc = 0; tc < 8; ++tc){
      const short8v bf = *(const short8v*)(Wt + (size_t)(tc*16 + fr)*HD + k0);
      acc[tc] = __builtin_amdgcn_mfma_f32_16x16x32_bf16(af, bf, acc[tc], 0, 0, 0);
    }
  }
  #pragma unroll
  for (int tc = 0; tc < 8; ++tc){
    const int col = tc*16 + fr;
    const float b = bias ? bias[col] : 0.f;
    #pragma unroll
    for (int j = 0; j < 4; ++j){
      const int r = row0 + fq*4 + j;
      if (r >= n) continue;
      float x = acc[tc][j] + b;
      if (doRelu) x = fmaxf(x, 0.f);
      if (outF) outF[(size_t)r*HD + col] = x;
      if (outB) outB[(size_t)r*HD + col] = f2bf(x);
    }
  }
}

// ---------------- MFMA GEMM, bf16 A (layer GEMMs) ----------------
__global__ __launch_bounds__(256) void gemm_hb_mfma(const ushort_t* __restrict__ inB,
    const ushort_t* __restrict__ Wt, const float* __restrict__ bias,
    float* __restrict__ outF, ushort_t* __restrict__ outB, int n, int doRelu)
{
  const int wid  = threadIdx.x >> 6;
  const int lane = threadIdx.x & 63;
  const int fr = lane & 15;
  const int fq = lane >> 4;
  const int row0 = blockIdx.x*GROWS + wid*16;
  const int arow = row0 + fr;
  const bool rowok = (arow < n);
  f32x4 acc[8];
  #pragma unroll
  for (int tc = 0; tc < 8; ++tc) acc[tc] = (f32x4)0.0f;
  #pragma unroll
  for (int ks = 0; ks < 4; ++ks){
    const int k0 = ks*32 + fq*8;
    short8v af = (short8v)0;
    if (rowok) af = *(const short8v*)(inB + (size_t)arow*HD + k0);
    #pragma unroll
    for (int tc = 0; tc < 8; ++tc){
      const short8v bf = *(const short8v*)(Wt + (size_t)(tc*16 + fr)*HD + k0);
      acc[tc] = __builtin_amdgcn_mfma_f32_16x16x32_bf16(af, bf, acc[tc], 0, 0, 0);
    }
  }
  #pragma unroll
  for (int tc = 0; tc < 8; ++tc){
    const int col = tc*16 + fr;
    const float b = bias ? bias[col] : 0.f;
    #pragma unroll
    for (int j = 0; j < 4; ++j){
      const int r = row0 + fq*4 + j;
      if (r >= n) continue;
      float x = acc[tc][j] + b;
      if (doRelu) x = fmaxf(x, 0.f);
      if (outF) outF[(size_t)r*HD + col] = x;
      if (outB) outB[(size_t)r*HD + col] = f2bf(x);
    }
  }
}

// ---------------- fused MFMA U/V GEMM, bf16 A: U = A@WtU^T + bu, V = A@WtV^T -------
__global__ __launch_bounds__(256) void gemm_uv_mfma(const ushort_t* __restrict__ inB,
    const ushort_t* __restrict__ WtU, const ushort_t* __restrict__ WtV,
    const float* __restrict__ biasU,
    ushort_t* __restrict__ outU, ushort_t* __restrict__ outV, int n)
{
  const int wid  = threadIdx.x >> 6;
  const int lane = threadIdx.x & 63;
  const int fr = lane & 15;
  const int fq = lane >> 4;
  const int row0 = blockIdx.x*GROWS + wid*16;
  const int arow = row0 + fr;
  const bool rowok = (arow < n);
  f32x4 aU[8], aV[8];
  #pragma unroll
  for (int tc = 0; tc < 8; ++tc){ aU[tc] = (f32x4)0.0f; aV[tc] = (f32x4)0.0f; }
  #pragma unroll
  for (int ks = 0; ks < 4; ++ks){
    const int k0 = ks*32 + fq*8;
    short8v af = (short8v)0;
    if (rowok) af = *(const short8v*)(inB + (size_t)arow*HD + k0);
    #pragma unroll
    for (int tc = 0; tc < 8; ++tc){
      const short8v bu = *(const short8v*)(WtU + (size_t)(tc*16 + fr)*HD + k0);
      aU[tc] = __builtin_amdgcn_mfma_f32_16x16x32_bf16(af, bu, aU[tc], 0, 0, 0);
      const short8v bv = *(const short8v*)(WtV + (size_t)(tc*16 + fr)*HD + k0);
      aV[tc] = __builtin_amdgcn_mfma_f32_16x16x32_bf16(af, bv, aV[tc], 0, 0, 0);
    }
  }
  #pragma unroll
  for (int tc = 0; tc < 8; ++tc){
    const int col = tc*16 + fr;
    const float b = biasU[col];
    #pragma unroll
    for (int j = 0; j < 4; ++j){
      const int r = row0 + fq*4 + j;
      if (r >= n) continue;
      outU[(size_t)r*HD + col] = f2bf(aU[tc][j] + b);
      outV[(size_t)r*HD + col] = f2bf(aV[tc][j]);
    }
  }
}

// ------------- fused mask+msg, 16-lane edge groups, 2-deep pipeline -------------
// Also writes hB2 = bf16(updated h) for the following bf16-A GEMM.
__global__ __launch_bounds__(256) void mask_msg_kernel(
    float* __restrict__ h,                  // in-place: read own row, write own row
    const ushort_t* __restrict__ U, const ushort_t* __restrict__ V,
    const ushort_t* __restrict__ hB,        // gather source: bf16 of pre-msg h
    ushort_t* __restrict__ hB2,             // out: bf16 of post-msg h
    const int* __restrict__ srcS, const int* __restrict__ eidS,
    const int* __restrict__ row_start,
    const float* __restrict__ Wm2, const float* __restrict__ bm2,
    float* __restrict__ maskOut)            // nullptr except final layer
{
  const int v = blockIdx.x*4 + (threadIdx.x >> 6);
  const int lane = threadIdx.x & 63;
  const int g   = lane >> 4;                // edge group 0..3
  const int sub = lane & 15;                // lane in group
  const float4 wA = ((const float4*)Wm2)[sub*2];      // cols sub*8..+3
  const float4 wB = ((const float4*)Wm2)[sub*2+1];    // cols sub*8+4..+7
  const float b2 = bm2[0];
  const uint4 vv = ((const uint4*)(V + (size_t)v*HD))[sub];
  float a0=0.f,a1=0.f,a2=0.f,a3=0.f,a4=0.f,a5=0.f,a6=0.f,a7=0.f;
  const int beg = row_start[v], end = row_start[v+1];
  int idx = beg + g;
  uint4 uu = make_uint4(0,0,0,0), hh = make_uint4(0,0,0,0);
  int e0 = 0;
  if (idx < end){
    const int s = srcS[idx];
    if (maskOut) e0 = eidS[idx];
    uu = ((const uint4*)(U  + (size_t)s*HD))[sub];
    hh = ((const uint4*)(hB + (size_t)s*HD))[sub];
  }
  while (idx < end){
    const int nidx = idx + 4;
    uint4 uuN = make_uint4(0,0,0,0), hhN = make_uint4(0,0,0,0);
    int eN = 0;
    if (nidx < end){
      const int sn = srcS[nidx];
      if (maskOut) eN = eidS[nidx];
      uuN = ((const uint4*)(U  + (size_t)sn*HD))[sub];
      hhN = ((const uint4*)(hB + (size_t)sn*HD))[sub];
    }
    float p;
    p = fmaxf(bflo(uu.x)+bflo(vv.x), 0.f) * wA.x;
    p = fmaf(fmaxf(bfhi(uu.x)+bfhi(vv.x), 0.f), wA.y, p);
    p = fmaf(fmaxf(bflo(uu.y)+bflo(vv.y), 0.f), wA.z, p);
    p = fmaf(fmaxf(bfhi(uu.y)+bfhi(vv.y), 0.f), wA.w, p);
    p = fmaf(fmaxf(bflo(uu.z)+bflo(vv.z), 0.f), wB.x, p);
    p = fmaf(fmaxf(bfhi(uu.z)+bfhi(vv.z), 0.f), wB.y, p);
    p = fmaf(fmaxf(bflo(uu.w)+bflo(vv.w), 0.f), wB.z, p);
    p = fmaf(fmaxf(bfhi(uu.w)+bfhi(vv.w), 0.f), wB.w, p);
    p += __shfl_xor(p, 1, 64);
    p += __shfl_xor(p, 2, 64);
    p += __shfl_xor(p, 4, 64);
    p += __shfl_xor(p, 8, 64);
    const float imp = sigmoidf_(p + b2);
    const float mk  = sigmoidf_((imp - 0.4f) * 2.0f);
    if (maskOut != nullptr && sub == 0) maskOut[e0] = mk;
    a0 = fmaf(mk, bflo(hh.x), a0);
    a1 = fmaf(mk, bfhi(hh.x), a1);
    a2 = fmaf(mk, bflo(hh.y), a2);
    a3 = fmaf(mk, bfhi(hh.y), a3);
    a4 = fmaf(mk, bflo(hh.z), a4);
    a5 = fmaf(mk, bfhi(hh.z), a5);
    a6 = fmaf(mk, bflo(hh.w), a6);
    a7 = fmaf(mk, bfhi(hh.w), a7);
    uu = uuN; hh = hhN; e0 = eN; idx = nidx;
  }
  a0 += __shfl_xor(a0, 16, 64); a0 += __shfl_xor(a0, 32, 64);
  a1 += __shfl_xor(a1, 16, 64); a1 += __shfl_xor(a1, 32, 64);
  a2 += __shfl_xor(a2, 16, 64); a2 += __shfl_xor(a2, 32, 64);
  a3 += __shfl_xor(a3, 16, 64); a3 += __shfl_xor(a3, 32, 64);
  a4 += __shfl_xor(a4, 16, 64); a4 += __shfl_xor(a4, 32, 64);
  a5 += __shfl_xor(a5, 16, 64); a5 += __shfl_xor(a5, 32, 64);
  a6 += __shfl_xor(a6, 16, 64); a6 += __shfl_xor(a6, 32, 64);
  a7 += __shfl_xor(a7, 16, 64); a7 += __shfl_xor(a7, 32, 64);
  if (g == 0){
    float4* hrow = (float4*)(h + (size_t)v*HD);
    float4 x0 = hrow[sub*2];
    float4 x1 = hrow[sub*2+1];
    x0.x += a0; x0.y += a1; x0.z += a2; x0.w += a3;
    x1.x += a4; x1.y += a5; x1.z += a6; x1.w += a7;
    hrow[sub*2]   = x0;
    hrow[sub*2+1] = x1;
    ushort4 p0, p1;
    p0.x = f2bf(x0.x); p0.y = f2bf(x0.y); p0.z = f2bf(x0.z); p0.w = f2bf(x0.w);
    p1.x = f2bf(x1.x); p1.y = f2bf(x1.y); p1.z = f2bf(x1.z); p1.w = f2bf(x1.w);
    ushort4* hb2row = (ushort4*)(hB2 + (size_t)v*HD) + sub*2;
    hb2row[0] = p0;
    hb2row[1] = p1;
  }
}

// ---------------- predictor ----------------
__global__ __launch_bounds__(128) void pred_kernel(const float* __restrict__ h,
  const float* __restrict__ Wp1, const float* __restrict__ bp1,
  const float* __restrict__ Wp2, const float* __restrict__ bp2,
  float* __restrict__ out0)
{
  __shared__ float red[128];
  const int t = threadIdx.x;
  float s = bp1[t];
  for (int k = 0; k < HD; ++k) s = fmaf(h[k], Wp1[k*HD + t], s);
  s = fmaxf(s, 0.f) * Wp2[t];
  red[t] = s;
  __syncthreads();
  for (int off = 64; off > 0; off >>= 1){
    if (t < off) red[t] += red[t + off];
    __syncthreads();
  }
  if (t == 0) out0[0] = red[0] + bp2[0];
}

extern "C" void kernel_launch(void* const* d_in, const int* in_sizes, int n_in,
                              void* d_out, int out_size, void* d_ws, size_t ws_size,
                              hipStream_t stream)
{
  (void)out_size;
  float* fOut = (float*)d_out;
  float* predOut = fOut;               // f32[0]
  float* maskOut = fOut + 1;           // f32[1 .. 1+NE)
  float* hOut    = fOut + 1 + NE;      // f32[1+NE ..)

  // ---- env tripwire (clean since R5; kept) ----
  static const int expSizes[14] = {6400000,1200000,16384,128,49152,384,32768,128,128,1,
                                   16384,128,128,1};
  const size_t NEEDED = 87100000;
  float diag = 0.f;
  if (n_in != 14) diag = 900.f + (float)n_in;
  else {
    for (int i = 0; i < 14; ++i)
      if (in_sizes[i] != expSizes[i]){ diag = 200.f + 16.f*(float)i; break; }
  }
  if (diag == 0.f && ws_size < NEEDED) diag = 5000.f + (float)(ws_size >> 20);

  if (diag != 0.f){
    write_scalar_kernel<<<1, 1, 0, stream>>>(predOut, diag);
    return;
  }

  const float* nf   = (const float*)d_in[0];
  const void*  ei   = d_in[1];
  const float* Wemb = (const float*)d_in[2];
  const float* bemb = (const float*)d_in[3];
  const float* Wgnn = (const float*)d_in[4];
  const float* bgnn = (const float*)d_in[5];
  const float* Wm1  = (const float*)d_in[6];
  const float* bm1  = (const float*)d_in[7];
  const float* Wm2  = (const float*)d_in[8];
  const float* bm2  = (const float*)d_in[9];
  const float* Wp1  = (const float*)d_in[10];
  const float* bp1  = (const float*)d_in[11];
  const float* Wp2  = (const float*)d_in[12];
  const float* bp2  = (const float*)d_in[13];

  float* hA    = (float*)d_ws;                        // h f32 (in-place)          25.6MB
  float* tmpU  = hA   + (size_t)NN*HD;                // Ub bf16 + hB2 bf16        25.6MB
  float* Vbuf  = tmpU + (size_t)NN*HD;                // Vb bf16 + hB bf16         25.6MB
  float* srcSf = Vbuf + (size_t)NN*HD;                // srcS int                   2.4MB
  int* srcS    = (int*)srcSf;                         // NE
  int* row_start = srcS + NE;                         // NN+1
  int* cursor  = row_start + (NN + 1);                // NN (reused for Wt after fill)
  int* counts  = cursor + NN;                         // NN
  int* eids    = counts + NN;                         // NE
  int* srcW    = eids + NE;                           // NE
  int* dstW    = srcW + NE;                           // NE
  int* flag    = dstW + NE;                           // 1
  int* partial = flag + 1;                            // NBLK
  int* bOff    = partial + NBLK;                      // NBLK

  ushort_t* Ub  = (ushort_t*)tmpU;                    // bf16 U
  ushort_t* hB2 = (ushort_t*)tmpU + (size_t)NN*HD;    // bf16 post-msg h
  ushort_t* Vb  = (ushort_t*)Vbuf;                    // bf16 V
  ushort_t* hB  = (ushort_t*)Vbuf + (size_t)NN*HD;    // bf16 pre-msg h

  // bf16 transposed weights in the cursor region (dead after fill_kernel):
  ushort_t* WtAll = (ushort_t*)cursor;
  ushort_t* WtEmb = WtAll;
  ushort_t* WtG0  = WtAll + 1*16384;
  ushort_t* WtG1  = WtAll + 2*16384;
  ushort_t* WtG2  = WtAll + 3*16384;
  ushort_t* WtU   = WtAll + 4*16384;
  ushort_t* WtV   = WtAll + 5*16384;

  // --- decode edge_index + dst histogram ---
  hipMemsetAsync(flag, 0, sizeof(int), stream);
  hipMemsetAsync(counts, 0, NN*sizeof(int), stream);
  detect_kernel<<<DET_SAMPLES/256, 256, 0, stream>>>((const unsigned int*)ei, flag);
  extract_kernel<<<(NE + 255)/256, 256, 0, stream>>>(ei, flag, srcW, dstW, counts);

  // --- CSR: hierarchical exclusive scan + fill (with CSR-ordered src) ---
  scanA_kernel<<<NBLK, 256, 0, stream>>>(counts, partial);
  scanB_kernel<<<1, 256, 0, stream>>>(partial, bOff);
  scanC_kernel<<<NBLK, 256, 0, stream>>>(counts, bOff, row_start, cursor);
  fill_kernel<<<(NE + 255)/256, 256, 0, stream>>>(dstW, srcW, cursor, eids, srcS);

  // --- weight convert+transpose, single dispatch (cursor region now dead) ---
  wcvt_all_kernel<<<384, 256, 0, stream>>>(Wemb, Wgnn, Wm1, WtAll);

  // h = relu(nf@Wemb+bemb): f32 + bf16 shadow (f32-A MFMA)
  gemm_h_mfma<<<GGRID, 256, 0, stream>>>(nf, WtEmb, bemb, hA, hB, NN, 1);

  const ushort_t* WtG[3] = {WtG0, WtG1, WtG2};
  for (int L = 0; L < 3; ++L){
    float* hnext = (L < 2) ? hA : hOut;               // h-gemm in-place for L<2
    ushort_t* hBnext = (L < 2) ? hB : nullptr;
    float* mOut = (L < 2) ? nullptr : maskOut;
    gemm_uv_mfma<<<GGRID, 256, 0, stream>>>(hB, WtU, WtV, bm1, Ub, Vb, NN);
    mask_msg_kernel<<<NN/4, 256, 0, stream>>>(hA, Ub, Vb, hB, hB2, srcS, eids, row_start,
                                              Wm2, bm2, mOut);
    gemm_hb_mfma<<<GGRID, 256, 0, stream>>>(hB2, WtG[L], bgnn + (size_t)L*HD,
                                            hnext, hBnext, NN, 1);
  }

  pred_kernel<<<1, 128, 0, stream>>>(hOut, Wp1, bp1, Wp2, bp2, predOut);
}